// Round 6
// baseline (199.803 us; speedup 1.0000x reference)
//
#include <hip/hip_runtime.h>

#define FDIM 128

typedef __attribute__((ext_vector_type(8))) short bf16x8;
typedef __attribute__((ext_vector_type(4))) float f32x4;

static __device__ __forceinline__ ushort f2bf(float f) {
    uint u = __float_as_uint(f);
    uint r = (u + 0x7FFF + ((u >> 16) & 1)) >> 16;
    return (ushort)r;
}
static __device__ __forceinline__ uint packbf(float lo, float hi) {
    return (uint)f2bf(lo) | ((uint)f2bf(hi) << 16);
}
static __device__ __forceinline__ float bflo(uint v) { return __uint_as_float(v << 16); }
static __device__ __forceinline__ float bfhi(uint v) { return __uint_as_float(v & 0xFFFF0000u); }

#define ACC8(A, V) do { \
    A[0] += bflo((V).x); A[1] += bfhi((V).x); \
    A[2] += bflo((V).y); A[3] += bfhi((V).y); \
    A[4] += bflo((V).z); A[5] += bfhi((V).z); \
    A[6] += bflo((V).w); A[7] += bfhi((V).w); } while (0)

// ---------------- prep: convert x + weights to bf16, bucket histogram, folded scan ----------------

__global__ void prep_kernel(const float* __restrict__ x, ushort* __restrict__ xb, int nx8,
                            const float* __restrict__ W1l, const float* __restrict__ W1r,
                            const float* __restrict__ W2l, const float* __restrict__ W2r,
                            const float* __restrict__ W3, ushort* __restrict__ wbuf,
                            const int* __restrict__ dst, int E, int* __restrict__ bcnt,
                            int* __restrict__ hdone, int* __restrict__ bbase,
                            int* __restrict__ bcur, int nb, int nconv, int nhist) {
    const int b = blockIdx.x;
    const int tid = threadIdx.x;
    if (b < nconv) {
        int i = b * 256 + tid;
        if (i < nx8) {
            const float* s = x + (size_t)i * 8;
            float4 a = *(const float4*)(s);
            float4 c = *(const float4*)(s + 4);
            uint4 o;
            o.x = packbf(a.x, a.y); o.y = packbf(a.z, a.w);
            o.z = packbf(c.x, c.y); o.w = packbf(c.z, c.w);
            *(uint4*)(xb + (size_t)i * 8) = o;
        }
    } else if (b < nconv + 36) {
        int c = (b - nconv) * 256 + tid;      // 0..9215 chunks of 8
        const float* s; ushort* d;
        if (c < 2048)      { s = W1l + (size_t)c * 8;          d = wbuf + (size_t)c * 8; }
        else if (c < 4096) { s = W1r + (size_t)(c - 2048) * 8; d = wbuf + 16384 + (size_t)(c - 2048) * 8; }
        else if (c < 6144) { s = W2l + (size_t)(c - 4096) * 8; d = wbuf + 32768 + (size_t)(c - 4096) * 8; }
        else if (c < 8192) { s = W2r + (size_t)(c - 6144) * 8; d = wbuf + 49152 + (size_t)(c - 6144) * 8; }
        else               { s = W3  + (size_t)(c - 8192) * 8; d = wbuf + 65536 + (size_t)(c - 8192) * 8; }
        float4 a = *(const float4*)(s);
        float4 cc = *(const float4*)(s + 4);
        uint4 o;
        o.x = packbf(a.x, a.y); o.y = packbf(a.z, a.w);
        o.z = packbf(cc.x, cc.y); o.w = packbf(cc.z, cc.w);
        *(uint4*)d = o;
    } else {
        __shared__ int lh[256];
        __shared__ int isLast;
        int hb = b - nconv - 36;
        lh[tid] = 0;
        __syncthreads();
        #pragma unroll
        for (int k = 0; k < 8; ++k) {
            int e = hb * 2048 + k * 256 + tid;
            if (e < E) atomicAdd(&lh[dst[e] >> 8], 1);
        }
        __syncthreads();
        if (lh[tid]) atomicAdd(&bcnt[tid], lh[tid]);
        // completion counter; last block runs the bucket scan (histogram is complete)
        __syncthreads();          // drains the global atomics (waitcnt before barrier)
        if (tid == 0) {
            __threadfence();
            isLast = (atomicAdd(hdone, 1) == nhist - 1);
        }
        __syncthreads();
        if (isLast && tid < 64) {
            __threadfence();      // invalidate L1 so bcnt reads are coherent
            volatile int* vb = bcnt;
            const int i0 = tid * 4;
            int v0 = (i0 + 0 < nb) ? vb[i0 + 0] : 0;
            int v1 = (i0 + 1 < nb) ? vb[i0 + 1] : 0;
            int v2 = (i0 + 2 < nb) ? vb[i0 + 2] : 0;
            int v3 = (i0 + 3 < nb) ? vb[i0 + 3] : 0;
            int s = v0 + v1 + v2 + v3;
            int incl = s;
            #pragma unroll
            for (int d = 1; d < 64; d <<= 1) {
                int t = __shfl_up(incl, d);
                if (tid >= d) incl += t;
            }
            int excl = incl - s;
            int e0 = excl, e1 = excl + v0, e2 = e1 + v1, e3 = e2 + v2;
            if (i0 + 0 < nb) { bbase[i0 + 0] = e0; bcur[i0 + 0] = e0; }
            if (i0 + 1 < nb) { bbase[i0 + 1] = e1; bcur[i0 + 1] = e1; }
            if (i0 + 2 < nb) { bbase[i0 + 2] = e2; bcur[i0 + 2] = e2; }
            if (i0 + 3 < nb) { bbase[i0 + 3] = e3; bcur[i0 + 3] = e3; }
            int total = __shfl(incl, 63);
            if (tid == 0) bbase[nb] = total;
        }
    }
}

// ---------------- bin edges into bucket-contiguous packed (src | dlow<<24) ----------------

__global__ void pair_scatter(const int* __restrict__ src, const int* __restrict__ dst,
                             int* __restrict__ bcur, uint* __restrict__ pairs, int E) {
    __shared__ int lh[256];
    __shared__ int gb[256];
    const int tid = threadIdx.x;
    lh[tid] = 0;
    __syncthreads();
    int ss[8], dd[8], sl[8];
    #pragma unroll
    for (int k = 0; k < 8; ++k) {
        int e = blockIdx.x * 2048 + k * 256 + tid;
        if (e < E) {
            ss[k] = src[e];
            dd[k] = dst[e];
            sl[k] = atomicAdd(&lh[dd[k] >> 8], 1);
        } else dd[k] = -1;
    }
    __syncthreads();
    if (lh[tid]) gb[tid] = atomicAdd(&bcur[tid], lh[tid]);
    __syncthreads();
    #pragma unroll
    for (int k = 0; k < 8; ++k) {
        if (dd[k] >= 0)
            pairs[gb[dd[k] >> 8] + sl[k]] = (uint)ss[k] | ((uint)(dd[k] & 255) << 24);
    }
}

// ---------------- per-bucket CSR: LDS count/scan/scatter ----------------

__global__ void bucket_csr(const uint* __restrict__ pairs, const int* __restrict__ bbase,
                           int* __restrict__ off, int* __restrict__ csr, int N) {
    __shared__ int cnt[256];
    __shared__ int base[256];
    __shared__ int cur[256];
    const int b = blockIdx.x;
    const int tid = threadIdx.x;
    const int p0 = bbase[b], p1 = bbase[b + 1];
    cnt[tid] = 0;
    __syncthreads();
    for (int p = p0 + tid; p < p1; p += 256) atomicAdd(&cnt[pairs[p] >> 24], 1);
    __syncthreads();
    if (tid < 64) {
        int i0 = tid * 4;
        int v0 = cnt[i0], v1 = cnt[i0 + 1], v2 = cnt[i0 + 2], v3 = cnt[i0 + 3];
        int s = v0 + v1 + v2 + v3;
        int incl = s;
        #pragma unroll
        for (int d = 1; d < 64; d <<= 1) {
            int t = __shfl_up(incl, d);
            if (tid >= d) incl += t;
        }
        int excl = incl - s;
        base[i0] = excl; base[i0 + 1] = excl + v0;
        base[i0 + 2] = excl + v0 + v1; base[i0 + 3] = excl + v0 + v1 + v2;
        cur[i0] = base[i0]; cur[i0 + 1] = base[i0 + 1];
        cur[i0 + 2] = base[i0 + 2]; cur[i0 + 3] = base[i0 + 3];
    }
    __syncthreads();
    int node = (b << 8) + tid;
    if (node <= N) off[node] = p0 + base[tid];
    for (int p = p0 + tid; p < p1; p += 256) {
        uint e = pairs[p];
        int slot = atomicAdd(&cur[e >> 24], 1);
        csr[p0 + slot] = (int)(e & 0xFFFFFF);
    }
}

// ---------------- fused SAGE layer: pair-interleaved gather-mean -> LDS, MFMA ----------------
// block = 256 thr (4 waves), 32 nodes/block. Wave w gathers its 8 nodes as 4
// PAIRS (A,B interleaved: 8 loads / 8 KB in flight, reduce of A overlaps B).
// Then MFMA: relu(As@Wl^T + Xs@Wr^T + b). HEAD=1 adds the W3 head in-LDS.

template<int HEAD>
__global__ void fused_sage(const ushort* __restrict__ feat, const int* __restrict__ off,
                           const int* __restrict__ csr,
                           const ushort* __restrict__ Wl, const ushort* __restrict__ Wr,
                           const float* __restrict__ bias,
                           const ushort* __restrict__ W3, const float* __restrict__ b3,
                           ushort* __restrict__ hout, float* __restrict__ fout, int n) {
    __shared__ __align__(16) ushort As[32 * FDIM];
    __shared__ __align__(16) ushort Xs[32 * FDIM];
    const int row0 = blockIdx.x * 32;
    const int lane = threadIdx.x & 63;
    const int wid  = threadIdx.x >> 6;

    // prefetch the wave's 9 CSR offsets (one load + shfl broadcast)
    const int offv = off[min(row0 + wid * 8 + min(lane, 8), n)];

    // stage self rows (coalesced)
    const float4 z4 = make_float4(0.f, 0.f, 0.f, 0.f);
    #pragma unroll
    for (int i = 0; i < 2; ++i) {
        int s = threadIdx.x + i * 256;
        int r = s >> 4, cch = s & 15;
        int row = row0 + r;
        float4 vx = (row < n) ? *(const float4*)(feat + (size_t)row * FDIM + cch * 8) : z4;
        *(float4*)(Xs + (r * 16 + (cch ^ (r & 7))) * 8) = vx;
    }

    const int g = lane >> 4;       // neighbor slot 0..3
    const int c = lane & 15;       // 16B chunk 0..15
    #define LDROW(s) (*(const uint4*)(feat + (size_t)(s) * FDIM + c * 8))

    #pragma unroll
    for (int i = 0; i < 4; ++i) {
        const int rA = wid * 8 + 2 * i;
        const int nodeA = row0 + rA, nodeB = nodeA + 1;
        const int j0A = __shfl(offv, 2 * i), j1A = __shfl(offv, 2 * i + 1);
        const int j1B = __shfl(offv, 2 * i + 2);
        float a[8] = {0.f, 0.f, 0.f, 0.f, 0.f, 0.f, 0.f, 0.f};
        float bacc[8] = {0.f, 0.f, 0.f, 0.f, 0.f, 0.f, 0.f, 0.f};
        int jA = j0A + g, jB = j1A + g;
        // both nodes deep: 8 loads in flight
        for (; jA + 12 < j1A && jB + 12 < j1B; jA += 16, jB += 16) {
            int sA0 = csr[jA], sA1 = csr[jA + 4], sA2 = csr[jA + 8], sA3 = csr[jA + 12];
            int sB0 = csr[jB], sB1 = csr[jB + 4], sB2 = csr[jB + 8], sB3 = csr[jB + 12];
            uint4 vA0 = LDROW(sA0), vA1 = LDROW(sA1), vA2 = LDROW(sA2), vA3 = LDROW(sA3);
            uint4 vB0 = LDROW(sB0), vB1 = LDROW(sB1), vB2 = LDROW(sB2), vB3 = LDROW(sB3);
            ACC8(a, vA0); ACC8(a, vA1); ACC8(a, vA2); ACC8(a, vA3);
            ACC8(bacc, vB0); ACC8(bacc, vB1); ACC8(bacc, vB2); ACC8(bacc, vB3);
        }
        // A tails
        for (; jA + 12 < j1A; jA += 16) {
            int s0 = csr[jA], s1 = csr[jA + 4], s2 = csr[jA + 8], s3 = csr[jA + 12];
            uint4 v0 = LDROW(s0), v1 = LDROW(s1), v2 = LDROW(s2), v3 = LDROW(s3);
            ACC8(a, v0); ACC8(a, v1); ACC8(a, v2); ACC8(a, v3);
        }
        for (; jA + 4 < j1A; jA += 8) {
            int s0 = csr[jA], s1 = csr[jA + 4];
            uint4 v0 = LDROW(s0), v1 = LDROW(s1);
            ACC8(a, v0); ACC8(a, v1);
        }
        for (; jA < j1A; jA += 4) {
            int s0 = csr[jA];
            uint4 v0 = LDROW(s0);
            ACC8(a, v0);
        }
        // B tails
        for (; jB + 12 < j1B; jB += 16) {
            int s0 = csr[jB], s1 = csr[jB + 4], s2 = csr[jB + 8], s3 = csr[jB + 12];
            uint4 v0 = LDROW(s0), v1 = LDROW(s1), v2 = LDROW(s2), v3 = LDROW(s3);
            ACC8(bacc, v0); ACC8(bacc, v1); ACC8(bacc, v2); ACC8(bacc, v3);
        }
        for (; jB + 4 < j1B; jB += 8) {
            int s0 = csr[jB], s1 = csr[jB + 4];
            uint4 v0 = LDROW(s0), v1 = LDROW(s1);
            ACC8(bacc, v0); ACC8(bacc, v1);
        }
        for (; jB < j1B; jB += 4) {
            int s0 = csr[jB];
            uint4 v0 = LDROW(s0);
            ACC8(bacc, v0);
        }
        // interleaved reduce (two independent chains)
        #pragma unroll
        for (int k = 0; k < 8; ++k) {
            a[k] += __shfl_xor(a[k], 16);
            bacc[k] += __shfl_xor(bacc[k], 16);
            a[k] += __shfl_xor(a[k], 32);
            bacc[k] += __shfl_xor(bacc[k], 32);
        }
        if (g == 0) {
            float invA = (nodeA < n) ? 1.0f / fmaxf((float)(j1A - j0A), 1.0f) : 0.f;
            float invB = (nodeB < n) ? 1.0f / fmaxf((float)(j1B - j1A), 1.0f) : 0.f;
            uint4 oA, oB;
            oA.x = packbf(a[0] * invA, a[1] * invA);
            oA.y = packbf(a[2] * invA, a[3] * invA);
            oA.z = packbf(a[4] * invA, a[5] * invA);
            oA.w = packbf(a[6] * invA, a[7] * invA);
            oB.x = packbf(bacc[0] * invB, bacc[1] * invB);
            oB.y = packbf(bacc[2] * invB, bacc[3] * invB);
            oB.z = packbf(bacc[4] * invB, bacc[5] * invB);
            oB.w = packbf(bacc[6] * invB, bacc[7] * invB);
            *(uint4*)(As + (rA * 16 + (c ^ (rA & 7))) * 8) = oA;
            *(uint4*)(As + ((rA + 1) * 16 + (c ^ ((rA + 1) & 7))) * 8) = oB;
        }
    }
    #undef LDROW
    __syncthreads();

    const int wrow = wid & 1;
    const int wcol = wid >> 1;
    const int lr = lane & 15;
    const int lk = lane >> 4;

    f32x4 acc[4];
    #pragma unroll
    for (int t = 0; t < 4; ++t) acc[t] = (f32x4){0.f, 0.f, 0.f, 0.f};

    const int arow = wrow * 16 + lr;
    #pragma unroll
    for (int ks = 0; ks < 4; ++ks) {
        bf16x8 a = *(const bf16x8*)(As + (arow * 16 + ((ks * 4 + lk) ^ (arow & 7))) * 8);
        #pragma unroll
        for (int t = 0; t < 4; ++t) {
            int wr = wcol * 64 + t * 16 + lr;
            bf16x8 bb = *(const bf16x8*)(Wl + (size_t)wr * FDIM + ks * 32 + lk * 8);
            acc[t] = __builtin_amdgcn_mfma_f32_16x16x32_bf16(a, bb, acc[t], 0, 0, 0);
        }
    }
    #pragma unroll
    for (int ks = 0; ks < 4; ++ks) {
        bf16x8 a = *(const bf16x8*)(Xs + (arow * 16 + ((ks * 4 + lk) ^ (arow & 7))) * 8);
        #pragma unroll
        for (int t = 0; t < 4; ++t) {
            int wr = wcol * 64 + t * 16 + lr;
            bf16x8 bb = *(const bf16x8*)(Wr + (size_t)wr * FDIM + ks * 32 + lk * 8);
            acc[t] = __builtin_amdgcn_mfma_f32_16x16x32_bf16(a, bb, acc[t], 0, 0, 0);
        }
    }

    if (HEAD == 0) {
        #pragma unroll
        for (int t = 0; t < 4; ++t) {
            int col = wcol * 64 + t * 16 + lr;
            float bc = bias[col];
            #pragma unroll
            for (int j = 0; j < 4; ++j) {
                int row = row0 + wrow * 16 + lk * 4 + j;
                if (row < n) {
                    float v = fmaxf(acc[t][j] + bc, 0.f);
                    hout[(size_t)row * FDIM + col] = f2bf(v);
                }
            }
        }
    } else {
        __syncthreads();
        #pragma unroll
        for (int t = 0; t < 4; ++t) {
            int col = wcol * 64 + t * 16 + lr;
            float bc = bias[col];
            #pragma unroll
            for (int j = 0; j < 4; ++j) {
                int r = wrow * 16 + lk * 4 + j;
                float v = fmaxf(acc[t][j] + bc, 0.f);
                As[(r * 16 + ((col >> 3) ^ (r & 7))) * 8 + (col & 7)] = f2bf(v);
            }
        }
        __syncthreads();

        f32x4 acc2[2];
        #pragma unroll
        for (int t = 0; t < 2; ++t) acc2[t] = (f32x4){0.f, 0.f, 0.f, 0.f};

        #pragma unroll
        for (int ks = 0; ks < 4; ++ks) {
            bf16x8 a = *(const bf16x8*)(As + (arow * 16 + ((ks * 4 + lk) ^ (arow & 7))) * 8);
            #pragma unroll
            for (int t = 0; t < 2; ++t) {
                int wr = wcol * 32 + t * 16 + lr;
                bf16x8 bb = *(const bf16x8*)(W3 + (size_t)wr * FDIM + ks * 32 + lk * 8);
                acc2[t] = __builtin_amdgcn_mfma_f32_16x16x32_bf16(a, bb, acc2[t], 0, 0, 0);
            }
        }

        #pragma unroll
        for (int t = 0; t < 2; ++t) {
            int col = wcol * 32 + t * 16 + lr;
            float bc = b3[col];
            #pragma unroll
            for (int j = 0; j < 4; ++j) {
                int row = row0 + wrow * 16 + lk * 4 + j;
                if (row < n) fout[(size_t)row * 64 + col] = acc2[t][j] + bc;
            }
        }
    }
}

// ---------------- launch ----------------

extern "C" void kernel_launch(void* const* d_in, const int* in_sizes, int n_in,
                              void* d_out, int out_size, void* d_ws, size_t ws_size,
                              hipStream_t stream) {
    const float* x   = (const float*)d_in[0];
    const int*   ei  = (const int*)d_in[1];
    const float* W1l = (const float*)d_in[2];
    const float* b1  = (const float*)d_in[3];
    const float* W1r = (const float*)d_in[4];
    const float* W2l = (const float*)d_in[5];
    const float* b2  = (const float*)d_in[6];
    const float* W2r = (const float*)d_in[7];
    const float* W3  = (const float*)d_in[8];
    const float* b3  = (const float*)d_in[9];
    float* out = (float*)d_out;

    const int N = in_sizes[0] / FDIM;   // 50000
    const int E = in_sizes[1] / 2;      // 800000
    const int* src = ei;
    const int* dst = ei + E;
    const int NBK = (N + 255) >> 8;     // 196

    char* ws = (char*)d_ws;
    size_t p = 0;
    auto alloc = [&](size_t bytes) {
        char* q = ws + p;
        p += (bytes + 255) & ~(size_t)255;
        return q;
    };
    int* ctrl    = (int*)alloc(272 * 4);          // bcnt[256] + hdone
    int* bcnt    = ctrl;
    int* hdone   = ctrl + 256;
    int* bbase   = (int*)alloc(260 * 4);
    int* bcur    = (int*)alloc(256 * 4);
    uint* pairs  = (uint*)alloc((size_t)E * 4);
    int* csr     = (int*)alloc((size_t)E * 4);
    int* off     = (int*)alloc((size_t)(N + 1) * 4);
    ushort* xb   = (ushort*)alloc((size_t)N * FDIM * 2);
    ushort* h1b  = (ushort*)alloc((size_t)N * FDIM * 2);
    ushort* wbuf = (ushort*)alloc(73728 * 2);
    ushort* w1l = wbuf, *w1r = wbuf + 16384, *w2l = wbuf + 32768,
           *w2r = wbuf + 49152, *w3 = wbuf + 65536;

    hipMemsetAsync(ctrl, 0, 257 * 4, stream);

    const int nx8   = N * FDIM / 8;         // 800000
    const int nconv = (nx8 + 255) / 256;    // 3125
    const int nhist = (E + 2047) / 2048;    // 391
    prep_kernel<<<nconv + 36 + nhist, 256, 0, stream>>>(
        x, xb, nx8, W1l, W1r, W2l, W2r, W3, wbuf, dst, E, bcnt,
        hdone, bbase, bcur, NBK, nconv, nhist);
    pair_scatter<<<(E + 2047) / 2048, 256, 0, stream>>>(src, dst, bcur, pairs, E);
    bucket_csr<<<NBK, 256, 0, stream>>>(pairs, bbase, off, csr, N);

    const int lgrid = (N + 31) / 32;
    fused_sage<0><<<lgrid, 256, 0, stream>>>(xb, off, csr, w1l, w1r, b1,
                                             (const ushort*)nullptr, (const float*)nullptr,
                                             h1b, (float*)nullptr, N);
    fused_sage<1><<<lgrid, 256, 0, stream>>>(h1b, off, csr, w2l, w2r, b2,
                                             w3, b3, (ushort*)nullptr, out, N);
}

// Round 7
// 171.778 us; speedup vs baseline: 1.1631x; 1.1631x over previous
//
#include <hip/hip_runtime.h>

#define FDIM 128

typedef __attribute__((ext_vector_type(8))) short bf16x8;
typedef __attribute__((ext_vector_type(4))) float f32x4;

static __device__ __forceinline__ ushort f2bf(float f) {
    uint u = __float_as_uint(f);
    uint r = (u + 0x7FFF + ((u >> 16) & 1)) >> 16;
    return (ushort)r;
}
static __device__ __forceinline__ uint packbf(float lo, float hi) {
    return (uint)f2bf(lo) | ((uint)f2bf(hi) << 16);
}
static __device__ __forceinline__ float bflo(uint v) { return __uint_as_float(v << 16); }
static __device__ __forceinline__ float bfhi(uint v) { return __uint_as_float(v & 0xFFFF0000u); }

#define ACC8(A, V) do { \
    A[0] += bflo((V).x); A[1] += bfhi((V).x); \
    A[2] += bflo((V).y); A[3] += bfhi((V).y); \
    A[4] += bflo((V).z); A[5] += bfhi((V).z); \
    A[6] += bflo((V).w); A[7] += bfhi((V).w); } while (0)

// ---------------- prep: convert x + weights to bf16, bucket histogram, folded scan ----------------

__global__ void prep_kernel(const float* __restrict__ x, ushort* __restrict__ xb, int nx8,
                            const float* __restrict__ W1l, const float* __restrict__ W1r,
                            const float* __restrict__ W2l, const float* __restrict__ W2r,
                            const float* __restrict__ W3, ushort* __restrict__ wbuf,
                            const int* __restrict__ dst, int E, int* __restrict__ bcnt,
                            int* __restrict__ hdone, int* __restrict__ bbase,
                            int* __restrict__ bcur, int nb, int nconv, int nhist) {
    const int b = blockIdx.x;
    const int tid = threadIdx.x;
    if (b < nconv) {
        int i = b * 256 + tid;
        if (i < nx8) {
            const float* s = x + (size_t)i * 8;
            float4 a = *(const float4*)(s);
            float4 c = *(const float4*)(s + 4);
            uint4 o;
            o.x = packbf(a.x, a.y); o.y = packbf(a.z, a.w);
            o.z = packbf(c.x, c.y); o.w = packbf(c.z, c.w);
            *(uint4*)(xb + (size_t)i * 8) = o;
        }
    } else if (b < nconv + 36) {
        int c = (b - nconv) * 256 + tid;      // 0..9215 chunks of 8
        const float* s; ushort* d;
        if (c < 2048)      { s = W1l + (size_t)c * 8;          d = wbuf + (size_t)c * 8; }
        else if (c < 4096) { s = W1r + (size_t)(c - 2048) * 8; d = wbuf + 16384 + (size_t)(c - 2048) * 8; }
        else if (c < 6144) { s = W2l + (size_t)(c - 4096) * 8; d = wbuf + 32768 + (size_t)(c - 4096) * 8; }
        else if (c < 8192) { s = W2r + (size_t)(c - 6144) * 8; d = wbuf + 49152 + (size_t)(c - 6144) * 8; }
        else               { s = W3  + (size_t)(c - 8192) * 8; d = wbuf + 65536 + (size_t)(c - 8192) * 8; }
        float4 a = *(const float4*)(s);
        float4 cc = *(const float4*)(s + 4);
        uint4 o;
        o.x = packbf(a.x, a.y); o.y = packbf(a.z, a.w);
        o.z = packbf(cc.x, cc.y); o.w = packbf(cc.z, cc.w);
        *(uint4*)d = o;
    } else {
        __shared__ int lh[256];
        __shared__ int isLast;
        int hb = b - nconv - 36;
        lh[tid] = 0;
        __syncthreads();
        #pragma unroll
        for (int k = 0; k < 8; ++k) {
            int e = hb * 2048 + k * 256 + tid;
            if (e < E) atomicAdd(&lh[dst[e] >> 8], 1);
        }
        __syncthreads();
        if (lh[tid]) atomicAdd(&bcnt[tid], lh[tid]);
        __syncthreads();
        if (tid == 0) {
            __threadfence();
            isLast = (atomicAdd(hdone, 1) == nhist - 1);
        }
        __syncthreads();
        if (isLast && tid < 64) {
            __threadfence();
            volatile int* vb = bcnt;
            const int i0 = tid * 4;
            int v0 = (i0 + 0 < nb) ? vb[i0 + 0] : 0;
            int v1 = (i0 + 1 < nb) ? vb[i0 + 1] : 0;
            int v2 = (i0 + 2 < nb) ? vb[i0 + 2] : 0;
            int v3 = (i0 + 3 < nb) ? vb[i0 + 3] : 0;
            int s = v0 + v1 + v2 + v3;
            int incl = s;
            #pragma unroll
            for (int d = 1; d < 64; d <<= 1) {
                int t = __shfl_up(incl, d);
                if (tid >= d) incl += t;
            }
            int excl = incl - s;
            int e0 = excl, e1 = excl + v0, e2 = e1 + v1, e3 = e2 + v2;
            if (i0 + 0 < nb) { bbase[i0 + 0] = e0; bcur[i0 + 0] = e0; }
            if (i0 + 1 < nb) { bbase[i0 + 1] = e1; bcur[i0 + 1] = e1; }
            if (i0 + 2 < nb) { bbase[i0 + 2] = e2; bcur[i0 + 2] = e2; }
            if (i0 + 3 < nb) { bbase[i0 + 3] = e3; bcur[i0 + 3] = e3; }
            int total = __shfl(incl, 63);
            if (tid == 0) bbase[nb] = total;
        }
    }
}

// ---------------- bin edges into bucket-contiguous packed (src | dlow<<24) ----------------

__global__ void pair_scatter(const int* __restrict__ src, const int* __restrict__ dst,
                             int* __restrict__ bcur, uint* __restrict__ pairs, int E) {
    __shared__ int lh[256];
    __shared__ int gb[256];
    const int tid = threadIdx.x;
    lh[tid] = 0;
    __syncthreads();
    int ss[8], dd[8], sl[8];
    #pragma unroll
    for (int k = 0; k < 8; ++k) {
        int e = blockIdx.x * 2048 + k * 256 + tid;
        if (e < E) {
            ss[k] = src[e];
            dd[k] = dst[e];
            sl[k] = atomicAdd(&lh[dd[k] >> 8], 1);
        } else dd[k] = -1;
    }
    __syncthreads();
    if (lh[tid]) gb[tid] = atomicAdd(&bcur[tid], lh[tid]);
    __syncthreads();
    #pragma unroll
    for (int k = 0; k < 8; ++k) {
        if (dd[k] >= 0)
            pairs[gb[dd[k] >> 8] + sl[k]] = (uint)ss[k] | ((uint)(dd[k] & 255) << 24);
    }
}

// ---------------- per-bucket CSR: LDS count/scan/scatter ----------------

__global__ void bucket_csr(const uint* __restrict__ pairs, const int* __restrict__ bbase,
                           int* __restrict__ off, int* __restrict__ csr, int N) {
    __shared__ int cnt[256];
    __shared__ int base[256];
    __shared__ int cur[256];
    const int b = blockIdx.x;
    const int tid = threadIdx.x;
    const int p0 = bbase[b], p1 = bbase[b + 1];
    cnt[tid] = 0;
    __syncthreads();
    for (int p = p0 + tid; p < p1; p += 256) atomicAdd(&cnt[pairs[p] >> 24], 1);
    __syncthreads();
    if (tid < 64) {
        int i0 = tid * 4;
        int v0 = cnt[i0], v1 = cnt[i0 + 1], v2 = cnt[i0 + 2], v3 = cnt[i0 + 3];
        int s = v0 + v1 + v2 + v3;
        int incl = s;
        #pragma unroll
        for (int d = 1; d < 64; d <<= 1) {
            int t = __shfl_up(incl, d);
            if (tid >= d) incl += t;
        }
        int excl = incl - s;
        base[i0] = excl; base[i0 + 1] = excl + v0;
        base[i0 + 2] = excl + v0 + v1; base[i0 + 3] = excl + v0 + v1 + v2;
        cur[i0] = base[i0]; cur[i0 + 1] = base[i0 + 1];
        cur[i0 + 2] = base[i0 + 2]; cur[i0 + 3] = base[i0 + 3];
    }
    __syncthreads();
    int node = (b << 8) + tid;
    if (node <= N) off[node] = p0 + base[tid];
    for (int p = p0 + tid; p < p1; p += 256) {
        uint e = pairs[p];
        int slot = atomicAdd(&cur[e >> 24], 1);
        csr[p0 + slot] = (int)(e & 0xFFFFFF);
    }
}

// ---------------- fused SAGE layer, 16-row tiles ----------------
// block = 256 thr (4 waves), 16 nodes/block, grid = 3125 (>8 blocks/CU resident cap).
// Gather: wave w gathers nodes w*4..w*4+3 (one at a time, quarter-wave slots).
// MFMA: operand-split: waves op=0 compute As@Wl^T, op=1 compute Xs@Wr^T -> psum LDS,
// then op=0 merges + bias + relu. HEAD=1: h2 tile back into As, second MFMA with W3.

#define PS 132   // psum row stride (floats), padded to kill bank conflicts

template<int HEAD>
__global__ __launch_bounds__(256, 8)
void fused_sage(const ushort* __restrict__ feat, const int* __restrict__ off,
                const int* __restrict__ csr,
                const ushort* __restrict__ Wl, const ushort* __restrict__ Wr,
                const float* __restrict__ bias,
                const ushort* __restrict__ W3, const float* __restrict__ b3,
                ushort* __restrict__ hout, float* __restrict__ fout, int n) {
    __shared__ __align__(16) ushort As[16 * FDIM];
    __shared__ __align__(16) ushort Xs[16 * FDIM];
    __shared__ __align__(16) float psum[16 * PS];
    const int row0 = blockIdx.x * 16;
    const int lane = threadIdx.x & 63;
    const int wid  = threadIdx.x >> 6;

    // stage self rows: 16 rows x 16 chunks = 256 threads, one 16B load each
    {
        int r = threadIdx.x >> 4, cch = threadIdx.x & 15;
        int row = row0 + r;
        float4 vx = make_float4(0.f, 0.f, 0.f, 0.f);
        if (row < n) vx = *(const float4*)(feat + (size_t)row * FDIM + cch * 8);
        *(float4*)(Xs + (r * 16 + (cch ^ (r & 7))) * 8) = vx;
    }

    // gather-mean: 4 nodes per wave, sequential; quarter-wave neighbor slots
    const int g = lane >> 4;
    const int c = lane & 15;
    #define LDROW(s) (*(const uint4*)(feat + (size_t)(s) * FDIM + c * 8))
    for (int i = 0; i < 4; ++i) {
        const int r = wid * 4 + i;
        const int node = row0 + r;
        float a[8] = {0.f, 0.f, 0.f, 0.f, 0.f, 0.f, 0.f, 0.f};
        float inv = 0.f;
        if (node < n) {
            const int j0 = off[node], j1 = off[node + 1];
            int j = j0 + g;
            for (; j + 12 < j1; j += 16) {
                int s0 = csr[j], s1 = csr[j + 4], s2 = csr[j + 8], s3 = csr[j + 12];
                uint4 v0 = LDROW(s0), v1 = LDROW(s1), v2 = LDROW(s2), v3 = LDROW(s3);
                ACC8(a, v0); ACC8(a, v1); ACC8(a, v2); ACC8(a, v3);
            }
            for (; j + 4 < j1; j += 8) {
                int s0 = csr[j], s1 = csr[j + 4];
                uint4 v0 = LDROW(s0), v1 = LDROW(s1);
                ACC8(a, v0); ACC8(a, v1);
            }
            for (; j < j1; j += 4) {
                uint4 v0 = LDROW(csr[j]);
                ACC8(a, v0);
            }
            inv = 1.0f / fmaxf((float)(j1 - j0), 1.0f);
        }
        #pragma unroll
        for (int k = 0; k < 8; ++k) {
            a[k] += __shfl_xor(a[k], 16);
            a[k] += __shfl_xor(a[k], 32);
        }
        if (g == 0) {
            uint4 o;
            o.x = packbf(a[0] * inv, a[1] * inv);
            o.y = packbf(a[2] * inv, a[3] * inv);
            o.z = packbf(a[4] * inv, a[5] * inv);
            o.w = packbf(a[6] * inv, a[7] * inv);
            *(uint4*)(As + (r * 16 + (c ^ (r & 7))) * 8) = o;
        }
    }
    #undef LDROW
    __syncthreads();

    // MFMA: wave role (op, half)
    const int op   = wid >> 1;          // 0: As@Wl, 1: Xs@Wr
    const int half = wid & 1;           // column half (64 cols)
    const int lr = lane & 15;
    const int lk = lane >> 4;
    const ushort* Atile = op ? Xs : As;
    const ushort* W     = op ? Wr : Wl;

    f32x4 acc[4];
    #pragma unroll
    for (int t = 0; t < 4; ++t) acc[t] = (f32x4){0.f, 0.f, 0.f, 0.f};

    #pragma unroll
    for (int ks = 0; ks < 4; ++ks) {
        bf16x8 a = *(const bf16x8*)(Atile + (lr * 16 + ((ks * 4 + lk) ^ (lr & 7))) * 8);
        #pragma unroll
        for (int t = 0; t < 4; ++t) {
            int wr = half * 64 + t * 16 + lr;
            bf16x8 bb = *(const bf16x8*)(W + (size_t)wr * FDIM + ks * 32 + lk * 8);
            acc[t] = __builtin_amdgcn_mfma_f32_16x16x32_bf16(a, bb, acc[t], 0, 0, 0);
        }
    }

    if (op == 1) {
        #pragma unroll
        for (int t = 0; t < 4; ++t) {
            #pragma unroll
            for (int j = 0; j < 4; ++j)
                psum[(lk * 4 + j) * PS + half * 64 + t * 16 + lr] = acc[t][j];
        }
    }
    __syncthreads();

    if (op == 0) {
        #pragma unroll
        for (int t = 0; t < 4; ++t) {
            int col = half * 64 + t * 16 + lr;
            float bc = bias[col];
            #pragma unroll
            for (int j = 0; j < 4; ++j) {
                int r = lk * 4 + j;
                float v = fmaxf(acc[t][j] + psum[r * PS + col] + bc, 0.f);
                if (HEAD == 0) {
                    int row = row0 + r;
                    if (row < n) hout[(size_t)row * FDIM + col] = f2bf(v);
                } else {
                    As[(r * 16 + ((col >> 3) ^ (r & 7))) * 8 + (col & 7)] = f2bf(v);
                }
            }
        }
    }

    if (HEAD == 1) {
        __syncthreads();
        // head: out = h2 @ W3^T + b3; each wave: 16 out cols (wid*16)
        f32x4 acc2 = (f32x4){0.f, 0.f, 0.f, 0.f};
        #pragma unroll
        for (int ks = 0; ks < 4; ++ks) {
            bf16x8 a = *(const bf16x8*)(As + (lr * 16 + ((ks * 4 + lk) ^ (lr & 7))) * 8);
            int wr = wid * 16 + lr;
            bf16x8 bb = *(const bf16x8*)(W3 + (size_t)wr * FDIM + ks * 32 + lk * 8);
            acc2 = __builtin_amdgcn_mfma_f32_16x16x32_bf16(a, bb, acc2, 0, 0, 0);
        }
        int col = wid * 16 + lr;
        float bc = b3[col];
        #pragma unroll
        for (int j = 0; j < 4; ++j) {
            int row = row0 + lk * 4 + j;
            if (row < n) fout[(size_t)row * 64 + col] = acc2[j] + bc;
        }
    }
}

// ---------------- launch ----------------

extern "C" void kernel_launch(void* const* d_in, const int* in_sizes, int n_in,
                              void* d_out, int out_size, void* d_ws, size_t ws_size,
                              hipStream_t stream) {
    const float* x   = (const float*)d_in[0];
    const int*   ei  = (const int*)d_in[1];
    const float* W1l = (const float*)d_in[2];
    const float* b1  = (const float*)d_in[3];
    const float* W1r = (const float*)d_in[4];
    const float* W2l = (const float*)d_in[5];
    const float* b2  = (const float*)d_in[6];
    const float* W2r = (const float*)d_in[7];
    const float* W3  = (const float*)d_in[8];
    const float* b3  = (const float*)d_in[9];
    float* out = (float*)d_out;

    const int N = in_sizes[0] / FDIM;   // 50000
    const int E = in_sizes[1] / 2;      // 800000
    const int* src = ei;
    const int* dst = ei + E;
    const int NBK = (N + 255) >> 8;     // 196

    char* ws = (char*)d_ws;
    size_t p = 0;
    auto alloc = [&](size_t bytes) {
        char* q = ws + p;
        p += (bytes + 255) & ~(size_t)255;
        return q;
    };
    int* ctrl    = (int*)alloc(272 * 4);          // bcnt[256] + hdone
    int* bcnt    = ctrl;
    int* hdone   = ctrl + 256;
    int* bbase   = (int*)alloc(260 * 4);
    int* bcur    = (int*)alloc(256 * 4);
    uint* pairs  = (uint*)alloc((size_t)E * 4);
    int* csr     = (int*)alloc((size_t)E * 4);
    int* off     = (int*)alloc((size_t)(N + 1) * 4);
    ushort* xb   = (ushort*)alloc((size_t)N * FDIM * 2);
    ushort* h1b  = (ushort*)alloc((size_t)N * FDIM * 2);
    ushort* wbuf = (ushort*)alloc(73728 * 2);
    ushort* w1l = wbuf, *w1r = wbuf + 16384, *w2l = wbuf + 32768,
           *w2r = wbuf + 49152, *w3 = wbuf + 65536;

    hipMemsetAsync(ctrl, 0, 257 * 4, stream);

    const int nx8   = N * FDIM / 8;         // 800000
    const int nconv = (nx8 + 255) / 256;    // 3125
    const int nhist = (E + 2047) / 2048;    // 391
    prep_kernel<<<nconv + 36 + nhist, 256, 0, stream>>>(
        x, xb, nx8, W1l, W1r, W2l, W2r, W3, wbuf, dst, E, bcnt,
        hdone, bbase, bcur, NBK, nconv, nhist);
    pair_scatter<<<(E + 2047) / 2048, 256, 0, stream>>>(src, dst, bcur, pairs, E);
    bucket_csr<<<NBK, 256, 0, stream>>>(pairs, bbase, off, csr, N);

    const int lgrid = (N + 15) / 16;    // 3125
    fused_sage<0><<<lgrid, 256, 0, stream>>>(xb, off, csr, w1l, w1r, b1,
                                             (const ushort*)nullptr, (const float*)nullptr,
                                             h1b, (float*)nullptr, N);
    fused_sage<1><<<lgrid, 256, 0, stream>>>(h1b, off, csr, w2l, w2r, b2,
                                             w3, b3, (ushort*)nullptr, out, N);
}